// Round 1
// baseline (192.165 us; speedup 1.0000x reference)
//
#include <hip/hip_runtime.h>
#include <hip/hip_bf16.h>

#define NB 2
#define LQ 256
#define LK 512
#define DM 512
#define NH 8
#define DKH 64
#define ROWS 8

__device__ __forceinline__ float fast_tanh(float x) {
    // tanh(x) = 1 - 2/(1+exp(2x)); exact at +-inf, ~1e-7 abs error
    float e = __expf(2.0f * x);
    float r = __builtin_amdgcn_rcpf(1.0f + e);
    return fmaf(-2.0f, r, 1.0f);
}

// ---- 64x64-tile fp32 GEMM body: C[row0:+64, col0:+64] = A(row0 rows,K=512) @ B(512x512)
__device__ __forceinline__ void gemm64(const float* __restrict__ A,
                                       const float* __restrict__ B,
                                       float* __restrict__ C,
                                       int row0, int col0)
{
    // As padded to 68: scalar transposed stores 2-way (free), float4 reads 16B-aligned
    __shared__ float As[16][68];
    __shared__ float Bs[16][64];
    const int tid = threadIdx.x;
    const int tx = tid & 15, ty = tid >> 4;
    const int lm = tid >> 2;           // A row in tile (0..63)
    const int lk = (tid & 3) << 2;     // k sub-offset 0,4,8,12
    const int bk = tid >> 4;           // B k row (0..15)
    const int bn = (tid & 15) << 2;    // B col 0..60
    float acc[4][4] = {};
    for (int k0 = 0; k0 < 512; k0 += 16) {
        float4 a4 = *reinterpret_cast<const float4*>(&A[(size_t)(row0 + lm) * 512 + k0 + lk]);
        float4 b4 = *reinterpret_cast<const float4*>(&B[(size_t)(k0 + bk) * 512 + col0 + bn]);
        __syncthreads();   // previous iteration's reads complete before overwrite
        As[lk + 0][lm] = a4.x;
        As[lk + 1][lm] = a4.y;
        As[lk + 2][lm] = a4.z;
        As[lk + 3][lm] = a4.w;
        *reinterpret_cast<float4*>(&Bs[bk][bn]) = b4;
        __syncthreads();
        #pragma unroll
        for (int kk = 0; kk < 16; ++kk) {
            float4 av = *reinterpret_cast<const float4*>(&As[kk][ty << 2]);
            float4 bv = *reinterpret_cast<const float4*>(&Bs[kk][tx << 2]);
            float a[4] = {av.x, av.y, av.z, av.w};
            float b[4] = {bv.x, bv.y, bv.z, bv.w};
            #pragma unroll
            for (int i = 0; i < 4; ++i)
                #pragma unroll
                for (int j = 0; j < 4; ++j)
                    acc[i][j] = fmaf(a[i], b[j], acc[i][j]);
        }
    }
    #pragma unroll
    for (int i = 0; i < 4; ++i) {
        float4 o = make_float4(acc[i][0], acc[i][1], acc[i][2], acc[i][3]);
        *reinterpret_cast<float4*>(&C[(size_t)(row0 + (ty << 2) + i) * 512 + col0 + (tx << 2)]) = o;
    }
}

// Fused Q/K/V projection: blockIdx.y picks segment (q rows 0..7, k 8..23, v 24..39)
__global__ __launch_bounds__(256) void proj_kernel(
    const float* __restrict__ query, const float* __restrict__ key,
    const float* __restrict__ value, const float* __restrict__ Wq,
    const float* __restrict__ Wk, const float* __restrict__ Wv,
    float* __restrict__ Qb, float* __restrict__ Kb, float* __restrict__ Vb)
{
    const int rb = blockIdx.y;
    const int cb = blockIdx.x;
    const float* A; const float* B; float* C; int row0;
    if (rb < 8)       { A = query; B = Wq; C = Qb; row0 = rb * 64; }
    else if (rb < 24) { A = key;   B = Wk; C = Kb; row0 = (rb - 8) * 64; }
    else              { A = value; B = Wv; C = Vb; row0 = (rb - 24) * 64; }
    gemm64(A, B, C, row0, cb * 64);
}

__global__ __launch_bounds__(256) void outproj_kernel(
    const float* __restrict__ xb, const float* __restrict__ Wo, float* __restrict__ out)
{
    gemm64(xb, Wo, out, blockIdx.y * 64, blockIdx.x * 64);
}

// Fused additive-attention: scores (lane=j, K transposed in LDS), softmax, PV (lane=d)
__global__ __launch_bounds__(256) void attn_kernel(
    const float* __restrict__ Qb, const float* __restrict__ Kb,
    const float* __restrict__ Vb, const int* __restrict__ mask,
    const float* __restrict__ wa, float* __restrict__ xb)
{
    __shared__ float KV[64 * 129];      // K transposed [64][129] (pad->2-way free) / V [128][64]
    __shared__ float wsm[ROWS][512];    // softmax weights
    __shared__ float qs[ROWS][64];
    __shared__ float was[64];

    const int tid = threadIdx.x;
    const int lane = tid & 63;
    const int wv = tid >> 6;            // wave 0..3, owns q-rows 2wv,2wv+1
    const int bid = blockIdx.x;         // b*256 + h*32 + qt
    const int qt = bid & 31;
    const int h = (bid >> 5) & 7;
    const int b = bid >> 8;
    const int q0row = qt * ROWS;

    for (int idx = tid; idx < ROWS * 64; idx += 256) {
        int r = idx >> 6, d = idx & 63;
        qs[r][d] = Qb[(size_t)(b * LQ + q0row + r) * DM + h * DKH + d];
    }
    if (tid < 64) was[tid] = wa[tid];

    const float* Kh = Kb + (size_t)b * LK * DM + h * DKH;
    const float* Vh = Vb + (size_t)b * LK * DM + h * DKH;

    float s[2][8];
    #pragma unroll
    for (int r = 0; r < 2; ++r)
        #pragma unroll
        for (int c = 0; c < 8; ++c) s[r][c] = 0.0f;

    const int r0 = wv * 2, r1 = wv * 2 + 1;

    // ---- score phase: lane = j within 64-chunk; s[row][r] is j = r*64+lane ----
    #pragma unroll
    for (int jt = 0; jt < 4; ++jt) {
        __syncthreads();                // qs visible / previous K-tile reads done
        #pragma unroll
        for (int it = 0; it < 8; ++it) {
            int f = it * 256 + tid;     // 2048 float4 loads
            int j = f >> 4;
            int d4 = (f & 15) << 2;
            float4 kv = *reinterpret_cast<const float4*>(&Kh[(size_t)(jt * 128 + j) * DM + d4]);
            KV[(d4 + 0) * 129 + j] = kv.x;
            KV[(d4 + 1) * 129 + j] = kv.y;
            KV[(d4 + 2) * 129 + j] = kv.z;
            KV[(d4 + 3) * 129 + j] = kv.w;
        }
        __syncthreads();
        #pragma unroll 4
        for (int d = 0; d < 64; ++d) {
            float wad = was[d];
            float qa = qs[r0][d];
            float qc = qs[r1][d];
            float k0 = KV[d * 129 + lane];
            float k1 = KV[d * 129 + 64 + lane];
            s[0][jt * 2 + 0] = fmaf(fast_tanh(qa + k0), wad, s[0][jt * 2 + 0]);
            s[0][jt * 2 + 1] = fmaf(fast_tanh(qa + k1), wad, s[0][jt * 2 + 1]);
            s[1][jt * 2 + 0] = fmaf(fast_tanh(qc + k0), wad, s[1][jt * 2 + 0]);
            s[1][jt * 2 + 1] = fmaf(fast_tanh(qc + k1), wad, s[1][jt * 2 + 1]);
        }
    }

    // ---- mask ----
    const int* mb = mask + b * LK;
    #pragma unroll
    for (int r = 0; r < 8; ++r) {
        if (mb[r * 64 + lane] == 0) { s[0][r] = -1e9f; s[1][r] = -1e9f; }
    }

    // ---- softmax (per q-row, across 8 regs x 64 lanes) ----
    #pragma unroll
    for (int row = 0; row < 2; ++row) {
        float mx = s[row][0];
        #pragma unroll
        for (int r = 1; r < 8; ++r) mx = fmaxf(mx, s[row][r]);
        #pragma unroll
        for (int off = 32; off > 0; off >>= 1) mx = fmaxf(mx, __shfl_xor(mx, off));
        float p[8]; float l = 0.0f;
        #pragma unroll
        for (int r = 0; r < 8; ++r) { p[r] = __expf(s[row][r] - mx); l += p[r]; }
        #pragma unroll
        for (int off = 32; off > 0; off >>= 1) l += __shfl_xor(l, off);
        float inv = __builtin_amdgcn_rcpf(l);
        #pragma unroll
        for (int r = 0; r < 8; ++r) wsm[wv * 2 + row][r * 64 + lane] = p[r] * inv;
    }

    // ---- PV phase: lane = d; weights broadcast from LDS as float4 ----
    float acc0 = 0.0f, acc1 = 0.0f;
    for (int jt = 0; jt < 4; ++jt) {
        __syncthreads();                // score-phase K reads / prev V reads done
        #pragma unroll
        for (int it = 0; it < 8; ++it) {
            int f = it * 256 + tid;
            int j = f >> 4;
            int d4 = (f & 15) << 2;
            float4 vv = *reinterpret_cast<const float4*>(&Vh[(size_t)(jt * 128 + j) * DM + d4]);
            *reinterpret_cast<float4*>(&KV[j * 64 + d4]) = vv;
        }
        __syncthreads();
        for (int jg = 0; jg < 32; ++jg) {
            int jb = jt * 128 + jg * 4;
            float4 w0 = *reinterpret_cast<const float4*>(&wsm[r0][jb]);
            float4 w1 = *reinterpret_cast<const float4*>(&wsm[r1][jb]);
            float v0 = KV[(jg * 4 + 0) * 64 + lane];
            float v1 = KV[(jg * 4 + 1) * 64 + lane];
            float v2 = KV[(jg * 4 + 2) * 64 + lane];
            float v3 = KV[(jg * 4 + 3) * 64 + lane];
            acc0 = fmaf(w0.x, v0, acc0); acc0 = fmaf(w0.y, v1, acc0);
            acc0 = fmaf(w0.z, v2, acc0); acc0 = fmaf(w0.w, v3, acc0);
            acc1 = fmaf(w1.x, v0, acc1); acc1 = fmaf(w1.y, v1, acc1);
            acc1 = fmaf(w1.z, v2, acc1); acc1 = fmaf(w1.w, v3, acc1);
        }
    }
    xb[(size_t)(b * LQ + q0row + r0) * DM + h * DKH + lane] = acc0;
    xb[(size_t)(b * LQ + q0row + r1) * DM + h * DKH + lane] = acc1;
}

extern "C" void kernel_launch(void* const* d_in, const int* in_sizes, int n_in,
                              void* d_out, int out_size, void* d_ws, size_t ws_size,
                              hipStream_t stream)
{
    const float* query = (const float*)d_in[0];
    const float* key   = (const float*)d_in[1];
    const float* value = (const float*)d_in[2];
    const int*   mask  = (const int*)d_in[3];
    const float* Wq    = (const float*)d_in[4];
    const float* Wk    = (const float*)d_in[5];
    const float* Wv    = (const float*)d_in[6];
    const float* Wo    = (const float*)d_in[7];
    const float* wa    = (const float*)d_in[8];
    float* out = (float*)d_out;

    float* base = (float*)d_ws;
    float* Qb = base;                    // 512*512
    float* Kb = Qb + 512 * 512;          // 1024*512
    float* Vb = Kb + 1024 * 512;         // 1024*512
    float* xb = Vb + 1024 * 512;         // 512*512

    proj_kernel<<<dim3(8, 40), 256, 0, stream>>>(query, key, value, Wq, Wk, Wv, Qb, Kb, Vb);
    attn_kernel<<<dim3(512), 256, 0, stream>>>(Qb, Kb, Vb, mask, wa, xb);
    outproj_kernel<<<dim3(8, 8), 256, 0, stream>>>(xb, Wo, out);
}

// Round 6
// 140.618 us; speedup vs baseline: 1.3666x; 1.3666x over previous
//
#include <hip/hip_runtime.h>

#define NB 2
#define LQ 256
#define LK 512
#define DM 512
#define NH 8
#define ROWS 4          // q-rows per attn block
#define C2F 2.885390081777927f   // 2*log2(e)
#define L2E 1.4426950408889634f

typedef __attribute__((ext_vector_type(8))) short short8;
typedef __attribute__((ext_vector_type(4))) float f32x4;

__device__ __forceinline__ ushort f2bf(float x) {
    unsigned int u = __float_as_uint(x);
    unsigned int r = (u + 0x7fffu + ((u >> 16) & 1u)) >> 16;   // RN-even
    return (ushort)r;
}
__device__ __forceinline__ float bf2f(ushort u) {
    return __uint_as_float(((unsigned int)u) << 16);
}

// ---------------- cvt inputs: [query;key;value] fp32 -> bf16 hi/lo, rows [2560][512]
__global__ __launch_bounds__(256) void cvt_in_kernel(
    const float* __restrict__ query, const float* __restrict__ key,
    const float* __restrict__ value, ushort* __restrict__ Ah, ushort* __restrict__ Al)
{
    int i4 = blockIdx.x * 256 + threadIdx.x;   // 327680 groups of 4
    int i = i4 * 4;
    const float* src;
    if (i < 262144)       src = query + i;
    else if (i < 786432)  src = key + (i - 262144);
    else                  src = value + (i - 786432);
    float4 x = *reinterpret_cast<const float4*>(src);
    ushort h0 = f2bf(x.x), h1 = f2bf(x.y), h2 = f2bf(x.z), h3 = f2bf(x.w);
    ushort4 hv = make_ushort4(h0, h1, h2, h3);
    ushort4 lv = make_ushort4(f2bf(x.x - bf2f(h0)), f2bf(x.y - bf2f(h1)),
                              f2bf(x.z - bf2f(h2)), f2bf(x.w - bf2f(h3)));
    *reinterpret_cast<ushort4*>(&Ah[i]) = hv;
    *reinterpret_cast<ushort4*>(&Al[i]) = lv;
}

// ---------------- cvt+transpose weights: W[k][n] fp32 -> Wt[widx][n][k] bf16 hi/lo
__global__ __launch_bounds__(256) void cvt_w_kernel(
    const float* __restrict__ Wq, const float* __restrict__ Wk,
    const float* __restrict__ Wv, const float* __restrict__ Wo,
    ushort* __restrict__ Wth, ushort* __restrict__ Wtl)
{
    __shared__ float T[32][33];
    const int widx = blockIdx.z;
    const float* W = (widx == 0) ? Wq : (widx == 1) ? Wk : (widx == 2) ? Wv : Wo;
    const int nt = blockIdx.x, kt = blockIdx.y;
    const int tid = threadIdx.x;
    const int rr = tid >> 3, c4 = tid & 7;
    float4 v = *reinterpret_cast<const float4*>(&W[(size_t)(kt * 32 + rr) * 512 + nt * 32 + c4 * 4]);
    T[c4 * 4 + 0][rr] = v.x;
    T[c4 * 4 + 1][rr] = v.y;
    T[c4 * 4 + 2][rr] = v.z;
    T[c4 * 4 + 3][rr] = v.w;
    __syncthreads();
    const int nr = tid >> 3, k4 = tid & 7;
    float x0 = T[nr][k4 * 4 + 0], x1 = T[nr][k4 * 4 + 1];
    float x2 = T[nr][k4 * 4 + 2], x3 = T[nr][k4 * 4 + 3];
    ushort h0 = f2bf(x0), h1 = f2bf(x1), h2 = f2bf(x2), h3 = f2bf(x3);
    size_t o = (size_t)widx * 262144 + (size_t)(nt * 32 + nr) * 512 + kt * 32 + k4 * 4;
    *reinterpret_cast<ushort4*>(&Wth[o]) = make_ushort4(h0, h1, h2, h3);
    *reinterpret_cast<ushort4*>(&Wtl[o]) = make_ushort4(
        f2bf(x0 - bf2f(h0)), f2bf(x1 - bf2f(h1)), f2bf(x2 - bf2f(h2)), f2bf(x3 - bf2f(h3)));
}

// ---------------- bf16 split-3 MFMA GEMM, 64x64 tile, K=512
// A: [*][512] row-major bf16 (hi/lo). Bt: [n][k] bf16 (hi/lo). C: fp32 [*][512].
__device__ __forceinline__ void gemm64_bf16(
    const ushort* __restrict__ Ah, const ushort* __restrict__ Al, int arow0,
    const ushort* __restrict__ Bth, const ushort* __restrict__ Btl,
    float* __restrict__ C, int crow0, int col0)
{
    __shared__ __align__(16) ushort AsH[64 * 40];  // stride 40 ushorts = 80B (16B-mult, ~2-way banks)
    __shared__ __align__(16) ushort AsL[64 * 40];
    __shared__ __align__(16) ushort BsH[64 * 40];
    __shared__ __align__(16) ushort BsL[64 * 40];
    const int tid = threadIdx.x;
    const int lane = tid & 63;
    const int w = tid >> 6, wr = w >> 1, wc = w & 1;
    const int srow = tid >> 2, sk8 = (tid & 3) * 8;

    f32x4 acc[2][2];
    #pragma unroll
    for (int i = 0; i < 2; ++i)
        #pragma unroll
        for (int j = 0; j < 2; ++j) acc[i][j] = (f32x4)0.0f;

    const int fr_row = (lane & 15), fk8 = (lane >> 4) * 8;

    for (int k0 = 0; k0 < 512; k0 += 32) {
        short8 gah = *reinterpret_cast<const short8*>(&Ah[(size_t)(arow0 + srow) * 512 + k0 + sk8]);
        short8 gal = *reinterpret_cast<const short8*>(&Al[(size_t)(arow0 + srow) * 512 + k0 + sk8]);
        short8 gbh = *reinterpret_cast<const short8*>(&Bth[(size_t)(col0 + srow) * 512 + k0 + sk8]);
        short8 gbl = *reinterpret_cast<const short8*>(&Btl[(size_t)(col0 + srow) * 512 + k0 + sk8]);
        __syncthreads();
        *reinterpret_cast<short8*>(&AsH[srow * 40 + sk8]) = gah;
        *reinterpret_cast<short8*>(&AsL[srow * 40 + sk8]) = gal;
        *reinterpret_cast<short8*>(&BsH[srow * 40 + sk8]) = gbh;
        *reinterpret_cast<short8*>(&BsL[srow * 40 + sk8]) = gbl;
        __syncthreads();
        short8 ah[2], al[2], bh[2], bl[2];
        #pragma unroll
        for (int fr = 0; fr < 2; ++fr) {
            int r = wr * 32 + fr * 16 + fr_row;
            ah[fr] = *reinterpret_cast<const short8*>(&AsH[r * 40 + fk8]);
            al[fr] = *reinterpret_cast<const short8*>(&AsL[r * 40 + fk8]);
        }
        #pragma unroll
        for (int fc = 0; fc < 2; ++fc) {
            int n = wc * 32 + fc * 16 + fr_row;
            bh[fc] = *reinterpret_cast<const short8*>(&BsH[n * 40 + fk8]);
            bl[fc] = *reinterpret_cast<const short8*>(&BsL[n * 40 + fk8]);
        }
        #pragma unroll
        for (int fr = 0; fr < 2; ++fr)
            #pragma unroll
            for (int fc = 0; fc < 2; ++fc) {
                acc[fr][fc] = __builtin_amdgcn_mfma_f32_16x16x32_bf16(ah[fr], bh[fc], acc[fr][fc], 0, 0, 0);
                acc[fr][fc] = __builtin_amdgcn_mfma_f32_16x16x32_bf16(ah[fr], bl[fc], acc[fr][fc], 0, 0, 0);
                acc[fr][fc] = __builtin_amdgcn_mfma_f32_16x16x32_bf16(al[fr], bh[fc], acc[fr][fc], 0, 0, 0);
            }
    }
    // C/D: col = lane&15, row = (lane>>4)*4 + i  [m89-verified]
    #pragma unroll
    for (int fr = 0; fr < 2; ++fr)
        #pragma unroll
        for (int fc = 0; fc < 2; ++fc)
            #pragma unroll
            for (int i = 0; i < 4; ++i) {
                int r = crow0 + wr * 32 + fr * 16 + (lane >> 4) * 4 + i;
                int c = col0 + wc * 32 + fc * 16 + (lane & 15);
                C[(size_t)r * 512 + c] = acc[fr][fc][i];
            }
}

__global__ __launch_bounds__(256) void qkv_gemm_kernel(
    const ushort* __restrict__ Ah, const ushort* __restrict__ Al,
    const ushort* __restrict__ Wth, const ushort* __restrict__ Wtl,
    float* __restrict__ Qb, float* __restrict__ Kb, float* __restrict__ Vb)
{
    const int rb = blockIdx.y, cb = blockIdx.x;
    int row0 = rb * 64;
    const ushort* bh; const ushort* bl; float* C; int crow0;
    if (row0 < 512)       { bh = Wth;           bl = Wtl;           C = Qb; crow0 = row0; }
    else if (row0 < 1536) { bh = Wth + 262144;  bl = Wtl + 262144;  C = Kb; crow0 = row0 - 512; }
    else                  { bh = Wth + 524288;  bl = Wtl + 524288;  C = Vb; crow0 = row0 - 1536; }
    gemm64_bf16(Ah, Al, row0, bh, bl, C, crow0, cb * 64);
}

__global__ __launch_bounds__(256) void out_gemm_kernel(
    const ushort* __restrict__ xh, const ushort* __restrict__ xl,
    const ushort* __restrict__ Woh, const ushort* __restrict__ Wol,
    float* __restrict__ out)
{
    gemm64_bf16(xh, xl, blockIdx.y * 64, Woh, Wol, out, blockIdx.y * 64, blockIdx.x * 64);
}

// ---------------- fused additive attention, 4 q-rows/block, grid 1024
__global__ __launch_bounds__(256) void attn_kernel(
    const float* __restrict__ Qb, const float* __restrict__ Kb,
    const float* __restrict__ Vb, const int* __restrict__ mask,
    const float* __restrict__ wa,
    ushort* __restrict__ xh, ushort* __restrict__ xl)
{
    __shared__ float qs[ROWS][64];      // pre-scaled by C2F
    __shared__ float was[64];
    __shared__ float wsm[ROWS][512];
    __shared__ float red[ROWS][8];
    __shared__ float xp[4][ROWS][64];

    const int tid = threadIdx.x;
    const int lane = tid & 63;
    const int w = tid >> 6;
    const int bid = blockIdx.x;          // b*512 + h*64 + qt
    const int qt = bid & 63;
    const int h = (bid >> 6) & 7;
    const int b = bid >> 9;
    const int q0 = qt * ROWS;

    if (tid < ROWS * 64) {
        int r = tid >> 6, d = tid & 63;
        qs[r][d] = Qb[(size_t)(b * LQ + q0 + r) * DM + h * 64 + d] * C2F;
    }
    if (tid < 64) was[tid] = wa[tid];
    __syncthreads();

    const float* Kh = Kb + ((size_t)b * LK) * DM + h * 64;
    const int jb = w * 128;
    const float* K0p = Kh + (size_t)(jb + lane) * DM;
    const float* K1p = K0p + (size_t)64 * DM;

    float s[ROWS][2];
    #pragma unroll
    for (int r = 0; r < ROWS; ++r) { s[r][0] = 0.0f; s[r][1] = 0.0f; }

    for (int db = 0; db < 8; ++db) {
        const int d0 = db * 8;
        float4 kA0 = *reinterpret_cast<const float4*>(&K0p[d0]);
        float4 kA1 = *reinterpret_cast<const float4*>(&K0p[d0 + 4]);
        float4 kB0 = *reinterpret_cast<const float4*>(&K1p[d0]);
        float4 kB1 = *reinterpret_cast<const float4*>(&K1p[d0 + 4]);
        float kc0[8], kc1[8], wav[8];
        kc0[0] = kA0.x * C2F; kc0[1] = kA0.y * C2F; kc0[2] = kA0.z * C2F; kc0[3] = kA0.w * C2F;
        kc0[4] = kA1.x * C2F; kc0[5] = kA1.y * C2F; kc0[6] = kA1.z * C2F; kc0[7] = kA1.w * C2F;
        kc1[0] = kB0.x * C2F; kc1[1] = kB0.y * C2F; kc1[2] = kB0.z * C2F; kc1[3] = kB0.w * C2F;
        kc1[4] = kB1.x * C2F; kc1[5] = kB1.y * C2F; kc1[6] = kB1.z * C2F; kc1[7] = kB1.w * C2F;
        float4 wv0 = *reinterpret_cast<const float4*>(&was[d0]);
        float4 wv1 = *reinterpret_cast<const float4*>(&was[d0 + 4]);
        wav[0] = wv0.x; wav[1] = wv0.y; wav[2] = wv0.z; wav[3] = wv0.w;
        wav[4] = wv1.x; wav[5] = wv1.y; wav[6] = wv1.z; wav[7] = wv1.w;
        #pragma unroll
        for (int r = 0; r < ROWS; ++r) {
            float4 q0f = *reinterpret_cast<const float4*>(&qs[r][d0]);
            float4 q1f = *reinterpret_cast<const float4*>(&qs[r][d0 + 4]);
            float qv[8];
            qv[0] = q0f.x; qv[1] = q0f.y; qv[2] = q0f.z; qv[3] = q0f.w;
            qv[4] = q1f.x; qv[5] = q1f.y; qv[6] = q1f.z; qv[7] = q1f.w;
            #pragma unroll
            for (int dd = 0; dd < 8; ++dd) {
                float e0 = __builtin_amdgcn_exp2f(qv[dd] + kc0[dd]);
                float r0 = __builtin_amdgcn_rcpf(1.0f + e0);
                float t0 = fmaf(-2.0f, r0, 1.0f);
                s[r][0] = fmaf(t0, wav[dd], s[r][0]);
                float e1 = __builtin_amdgcn_exp2f(qv[dd] + kc1[dd]);
                float r1 = __builtin_amdgcn_rcpf(1.0f + e1);
                float t1 = fmaf(-2.0f, r1, 1.0f);
                s[r][1] = fmaf(t1, wav[dd], s[r][1]);
            }
        }
    }

    // mask
    const int* mb = mask + b * LK;
    int m0 = mb[jb + lane], m1 = mb[jb + 64 + lane];
    #pragma unroll
    for (int r = 0; r < ROWS; ++r) {
        if (m0 == 0) s[r][0] = -1e9f;
        if (m1 == 0) s[r][1] = -1e9f;
    }

    // softmax over 512 = 4 waves x 2 chunks x 64 lanes
    #pragma unroll
    for (int r = 0; r < ROWS; ++r) {
        float mx = fmaxf(s[r][0], s[r][1]);
        #pragma unroll
        for (int off = 32; off > 0; off >>= 1) mx = fmaxf(mx, __shfl_xor(mx, off));
        if (lane == 0) red[r][w] = mx;
    }
    __syncthreads();
    float p[ROWS][2];
    #pragma unroll
    for (int r = 0; r < ROWS; ++r) {
        float gmx = fmaxf(fmaxf(red[r][0], red[r][1]), fmaxf(red[r][2], red[r][3]));
        p[r][0] = __builtin_amdgcn_exp2f((s[r][0] - gmx) * L2E);
        p[r][1] = __builtin_amdgcn_exp2f((s[r][1] - gmx) * L2E);
        float sm = p[r][0] + p[r][1];
        #pragma unroll
        for (int off = 32; off > 0; off >>= 1) sm += __shfl_xor(sm, off);
        if (lane == 0) red[r][4 + w] = sm;
    }
    __syncthreads();
    #pragma unroll
    for (int r = 0; r < ROWS; ++r) {
        float tot = (red[r][4] + red[r][5]) + (red[r][6] + red[r][7]);
        float inv = __builtin_amdgcn_rcpf(tot);
        wsm[r][jb + lane] = p[r][0] * inv;
        wsm[r][jb + 64 + lane] = p[r][1] * inv;
    }
    __syncthreads();

    // PV: wave w owns j-quarter [w*128, +128), all 4 rows; lane = d
    const float* Vh = Vb + ((size_t)b * LK) * DM + h * 64;
    float o0 = 0.0f, o1 = 0.0f, o2 = 0.0f, o3 = 0.0f;
    const int jq = w * 128;
    #pragma unroll 4
    for (int jj = 0; jj < 128; jj += 4) {
        const int j = jq + jj;
        float4 w0 = *reinterpret_cast<const float4*>(&wsm[0][j]);
        float4 w1 = *reinterpret_cast<const float4*>(&wsm[1][j]);
        float4 w2 = *reinterpret_cast<const float4*>(&wsm[2][j]);
        float4 w3 = *reinterpret_cast<const float4*>(&wsm[3][j]);
        float v0 = Vh[(size_t)(j + 0) * DM + lane];
        float v1 = Vh[(size_t)(j + 1) * DM + lane];
        float v2 = Vh[(size_t)(j + 2) * DM + lane];
        float v3 = Vh[(size_t)(j + 3) * DM + lane];
        o0 = fmaf(w0.x, v0, o0); o0 = fmaf(w0.y, v1, o0); o0 = fmaf(w0.z, v2, o0); o0 = fmaf(w0.w, v3, o0);
        o1 = fmaf(w1.x, v0, o1); o1 = fmaf(w1.y, v1, o1); o1 = fmaf(w1.z, v2, o1); o1 = fmaf(w1.w, v3, o1);
        o2 = fmaf(w2.x, v0, o2); o2 = fmaf(w2.y, v1, o2); o2 = fmaf(w2.z, v2, o2); o2 = fmaf(w2.w, v3, o2);
        o3 = fmaf(w3.x, v0, o3); o3 = fmaf(w3.y, v1, o3); o3 = fmaf(w3.z, v2, o3); o3 = fmaf(w3.w, v3, o3);
    }
    xp[w][0][lane] = o0;
    xp[w][1][lane] = o1;
    xp[w][2][lane] = o2;
    xp[w][3][lane] = o3;
    __syncthreads();
    // wave w reduces row w across the 4 j-quarters and stores
    {
        const int r = w;
        float acc = ((xp[0][r][lane] + xp[1][r][lane]) + (xp[2][r][lane] + xp[3][r][lane]));
        size_t oidx = (size_t)(b * LQ + q0 + r) * DM + h * 64 + lane;
        ushort hb = f2bf(acc);
        xh[oidx] = hb;
        xl[oidx] = f2bf(acc - bf2f(hb));
    }
}

extern "C" void kernel_launch(void* const* d_in, const int* in_sizes, int n_in,
                              void* d_out, int out_size, void* d_ws, size_t ws_size,
                              hipStream_t stream)
{
    const float* query = (const float*)d_in[0];
    const float* key   = (const float*)d_in[1];
    const float* value = (const float*)d_in[2];
    const int*   mask  = (const int*)d_in[3];
    const float* Wq    = (const float*)d_in[4];
    const float* Wk    = (const float*)d_in[5];
    const float* Wv    = (const float*)d_in[6];
    const float* Wo    = (const float*)d_in[7];
    const float* wa    = (const float*)d_in[8];
    float* out = (float*)d_out;

    char* W = (char*)d_ws;
    float*  Qb  = (float*)(W);                          // 512x512 f32   (1 MB)
    float*  Kb  = (float*)(W + 1048576);                // 1024x512 f32  (2 MB)
    float*  Vb  = (float*)(W + 3145728);                // 1024x512 f32  (2 MB)
    ushort* Ah  = (ushort*)(W + 5242880);               // 2560x512 bf16 (2.62 MB)
    ushort* Al  = (ushort*)(W + 7864320);
    ushort* Wth = (ushort*)(W + 10485760);              // 4x512x512 bf16 (2 MB)
    ushort* Wtl = (ushort*)(W + 12582912);
    ushort* xh  = (ushort*)(W + 14680064);              // 512x512 bf16 (0.5 MB)
    ushort* xl  = (ushort*)(W + 15204352);

    cvt_in_kernel<<<dim3(1280), 256, 0, stream>>>(query, key, value, Ah, Al);
    cvt_w_kernel<<<dim3(16, 16, 4), 256, 0, stream>>>(Wq, Wk, Wv, Wo, Wth, Wtl);
    qkv_gemm_kernel<<<dim3(8, 40), 256, 0, stream>>>(Ah, Al, Wth, Wtl, Qb, Kb, Vb);
    attn_kernel<<<dim3(1024), 256, 0, stream>>>(Qb, Kb, Vb, mask, wa, xh, xl);
    out_gemm_kernel<<<dim3(8, 8), 256, 0, stream>>>(xh, xl, Wth + 786432, Wtl + 786432, out);
}